// Round 2
// baseline (3496.642 us; speedup 1.0000x reference)
//
#include <hip/hip_runtime.h>
#include <cstdint>

#define N_NODES 100000
#define N_EDGES 300000

constexpr int BM = 64, BN = 64, BK = 32;

// C = (A @ B) * dinv[row] (+bias) ; optional second write C2 (strided concat buf)
__global__ __launch_bounds__(256)
void gemm_kernel(const float* __restrict__ A, int lda,
                 const float* __restrict__ B, int ldb,
                 float* __restrict__ C, int ldc,
                 float* __restrict__ C2, int ldc2,
                 const float* __restrict__ dinv,
                 const float* __restrict__ bias,
                 int M, int K)
{
    __shared__ float As[BK][BM + 4];   // A stored transposed: As[k][r]
    __shared__ float Bs[BK][BN + 4];

    const int tid = threadIdx.x;
    const int tx = tid & 15, ty = tid >> 4;
    const int row0 = blockIdx.x * BM, col0 = blockIdx.y * BN;

    float acc[4][4] = {};

    for (int k0 = 0; k0 < K; k0 += BK) {
#pragma unroll
        for (int it = 0; it < 2; ++it) {
            int r = (tid >> 3) + it * 32;
            int c = (tid & 7) << 2;
            float4 v = make_float4(0.f, 0.f, 0.f, 0.f);
            int gr = row0 + r;
            if (gr < M) v = *(const float4*)(A + (size_t)gr * lda + k0 + c);
            As[c + 0][r] = v.x; As[c + 1][r] = v.y;
            As[c + 2][r] = v.z; As[c + 3][r] = v.w;
        }
#pragma unroll
        for (int it = 0; it < 2; ++it) {
            int r = (tid >> 4) + it * 16;
            int c = (tid & 15) << 2;
            *(float4*)(&Bs[r][c]) = *(const float4*)(B + (size_t)(k0 + r) * ldb + col0 + c);
        }
        __syncthreads();
#pragma unroll
        for (int k = 0; k < BK; ++k) {
            float4 a4 = *(const float4*)(&As[k][ty << 2]);
            float4 b4 = *(const float4*)(&Bs[k][tx << 2]);
            float av[4] = {a4.x, a4.y, a4.z, a4.w};
            float bv[4] = {b4.x, b4.y, b4.z, b4.w};
#pragma unroll
            for (int i = 0; i < 4; ++i)
#pragma unroll
                for (int j = 0; j < 4; ++j)
                    acc[i][j] = fmaf(av[i], bv[j], acc[i][j]);
        }
        __syncthreads();
    }

#pragma unroll
    for (int i = 0; i < 4; ++i) {
        int gr = row0 + (ty << 2) + i;
        if (gr >= M) continue;
        float s = dinv ? dinv[gr] : 1.f;
        float out[4];
#pragma unroll
        for (int j = 0; j < 4; ++j) {
            int gc = col0 + (tx << 2) + j;
            float v = acc[i][j] * s;
            if (bias) v += bias[gc];
            out[j] = v;
        }
        float4 w = make_float4(out[0], out[1], out[2], out[3]);
        *(float4*)(C + (size_t)gr * ldc + col0 + (tx << 2)) = w;
        if (C2) *(float4*)(C2 + (size_t)gr * ldc2 + col0 + (tx << 2)) = w;
    }
}

// In-place final GEMM: out[N,512] = out @ B[512,512] + bias.
// BM=32 rows/block, full 512 cols per block => A-rows == C-rows, no cross-block
// hazard; all A reads precede the epilogue C write within a block.
constexpr int FBM = 32, FBK = 16;
__global__ __launch_bounds__(256)
void final_gemm(float* __restrict__ out, const float* __restrict__ B,
                const float* __restrict__ bias)
{
    __shared__ float As[FBK][FBM + 4];
    __shared__ float Bs[FBK][512];

    const int tid = threadIdx.x;
    const int tc = tid & 31, tr = tid >> 5;     // 8 x 32 thread grid
    const size_t row0 = (size_t)blockIdx.x * FBM;

    float acc[4][16] = {};

    for (int k0 = 0; k0 < 512; k0 += FBK) {
        if (tid < 128) {
            int r = tid >> 2;           // 0..31
            int c = (tid & 3) << 2;     // 0,4,8,12
            float4 v = *(const float4*)(out + (row0 + r) * 512 + k0 + c);
            As[c + 0][r] = v.x; As[c + 1][r] = v.y;
            As[c + 2][r] = v.z; As[c + 3][r] = v.w;
        }
#pragma unroll
        for (int it = 0; it < 8; ++it) {
            int li = tid + (it << 8);        // 0..2047 float4 index
            int r = li >> 7;                 // 128 float4 per row
            int c = (li & 127) << 2;
            *(float4*)(&Bs[r][c]) = *(const float4*)(B + (size_t)(k0 + r) * 512 + c);
        }
        __syncthreads();
#pragma unroll
        for (int k = 0; k < FBK; ++k) {
            float a[4];
            *(float4*)a = *(const float4*)(&As[k][tr << 2]);
            float b[16];
            // 4 col-chunks at stride 128: consecutive lanes -> consecutive
            // ds_read_b128 (conflict-free); lanes 32..63 broadcast-share.
#pragma unroll
            for (int jb = 0; jb < 4; ++jb)
                *(float4*)(b + (jb << 2)) = *(const float4*)(&Bs[k][(tc << 2) + (jb << 7)]);
#pragma unroll
            for (int i = 0; i < 4; ++i)
#pragma unroll
                for (int j = 0; j < 16; ++j)
                    acc[i][j] = fmaf(a[i], b[j], acc[i][j]);
        }
        __syncthreads();
    }

#pragma unroll
    for (int i = 0; i < 4; ++i) {
        size_t row = row0 + (tr << 2) + i;
#pragma unroll
        for (int jb = 0; jb < 4; ++jb) {
            int col = (tc << 2) + (jb << 7);
            float4 v;
            v.x = acc[i][(jb << 2) + 0] + bias[col + 0];
            v.y = acc[i][(jb << 2) + 1] + bias[col + 1];
            v.z = acc[i][(jb << 2) + 2] + bias[col + 2];
            v.w = acc[i][(jb << 2) + 3] + bias[col + 3];
            *(float4*)(out + row * 512 + col) = v;
        }
    }
}

__global__ __launch_bounds__(256)
void deg_init(float* deg, int n)
{
    int i = blockIdx.x * 256 + threadIdx.x;
    if (i < n) deg[i] = 1.f;   // self loop
}

__global__ __launch_bounds__(256)
void deg_count(const int* __restrict__ dst, float* __restrict__ deg, int e)
{
    int i = blockIdx.x * 256 + threadIdx.x;
    if (i < e) atomicAdd(&deg[dst[i]], 1.f);
}

__global__ __launch_bounds__(256)
void deg_rsqrt(float* deg, int n)
{
    int i = blockIdx.x * 256 + threadIdx.x;
    if (i < n) deg[i] = rsqrtf(deg[i]);   // deg >= 1 always
}

__global__ __launch_bounds__(256)
void transpose_kernel(const float* __restrict__ W, float* __restrict__ WT)
{
    int idx = blockIdx.x * 256 + threadIdx.x;   // 512*512
    int i = idx >> 9, j = idx & 511;
    WT[idx] = W[(j << 9) | i];                  // WT[i][j] = W[j][i]
}

// agg[dst] += g[src] ; agg lives in strided concat region of d_out
__global__ __launch_bounds__(256)
void scatter_kernel(const float* __restrict__ g,
                    float* __restrict__ agg, int ldagg,
                    const int* __restrict__ src, const int* __restrict__ dst,
                    int E, int F, int lg2c)
{
    int idx = blockIdx.x * 256 + threadIdx.x;
    int e = idx >> lg2c;
    if (e >= E) return;
    int c = (idx & ((1 << lg2c) - 1)) << 2;
    int s = src[e], d = dst[e];
    const float4 v = *(const float4*)(g + (size_t)s * F + c);
    float* p = agg + (size_t)d * ldagg + c;
    atomicAdd(p + 0, v.x);
    atomicAdd(p + 1, v.y);
    atomicAdd(p + 2, v.z);
    atomicAdd(p + 3, v.w);
}

// xc[:, off:off+F] = relu(dinv*agg + bias), in place
__global__ __launch_bounds__(256)
void finalize_kernel(float* __restrict__ xc, int ldc, int colOff,
                     const float* __restrict__ dinv, const float* __restrict__ bias,
                     int N, int lg2c)
{
    int idx = blockIdx.x * 256 + threadIdx.x;
    int row = idx >> lg2c;
    if (row >= N) return;
    int c = (idx & ((1 << lg2c) - 1)) << 2;
    float s = dinv[row];
    float* p = xc + (size_t)row * ldc + colOff + c;
    float4 v = *(float4*)p;
    v.x = fmaxf(fmaf(v.x, s, bias[c + 0]), 0.f);
    v.y = fmaxf(fmaf(v.y, s, bias[c + 1]), 0.f);
    v.z = fmaxf(fmaf(v.z, s, bias[c + 2]), 0.f);
    v.w = fmaxf(fmaf(v.w, s, bias[c + 3]), 0.f);
    *p = v.x; *(p + 1) = v.y; *(p + 2) = v.z; *(p + 3) = v.w;
}

extern "C" void kernel_launch(void* const* d_in, const int* in_sizes, int n_in,
                              void* d_out, int out_size, void* d_ws, size_t ws_size,
                              hipStream_t stream)
{
    const float* x  = (const float*)d_in[0];
    const float* W1 = (const float*)d_in[1];
    const float* b1 = (const float*)d_in[2];
    const float* W2 = (const float*)d_in[3];
    const float* b2 = (const float*)d_in[4];
    const float* W3 = (const float*)d_in[5];
    const float* b3 = (const float*)d_in[6];
    const float* W4 = (const float*)d_in[7];
    const float* b4 = (const float*)d_in[8];
    const int*   ei = (const int*)d_in[9];
    const int* src = ei;
    const int* dst = ei + N_EDGES;

    const int N = N_NODES, E = N_EDGES;

    // workspace layout: dinv | W4T | g  (~103.9 MB total)
    const size_t OFF_W4T = 401408;
    const size_t OFF_G   = OFF_W4T + 512 * 512 * 4;          // 1449984
    const size_t WS_NEED = OFF_G + (size_t)N * 256 * 4;      // 103,849,984
    if (ws_size < WS_NEED) return;  // clean failure instead of OOB container kill

    char* ws = (char*)d_ws;
    float* dinv = (float*)ws;
    float* W4T  = (float*)(ws + OFF_W4T);
    float* g    = (float*)(ws + OFF_G);
    float* xc   = (float*)d_out;   // concat buffer lives in d_out: [x1|x2|x3]

    dim3 blk(256);
    int gx = (N + BM - 1) / BM;   // 1563

    deg_init<<<dim3((N + 255) / 256), blk, 0, stream>>>(dinv, N);
    deg_count<<<dim3((E + 255) / 256), blk, 0, stream>>>(dst, dinv, E);
    deg_rsqrt<<<dim3((N + 255) / 256), blk, 0, stream>>>(dinv, N);
    transpose_kernel<<<dim3(1024), blk, 0, stream>>>(W4, W4T);

    // ---- conv1: [N,512]x[512,256] -> xc cols [0,256) ----
    gemm_kernel<<<dim3(gx, 4), blk, 0, stream>>>(
        x, 512, W1, 256, g, 256, xc + 0, 512, dinv, (const float*)nullptr, N, 512);
    scatter_kernel<<<dim3((E * 64 + 255) / 256), blk, 0, stream>>>(
        g, xc + 0, 512, src, dst, E, 256, 6);
    finalize_kernel<<<dim3((N * 64 + 255) / 256), blk, 0, stream>>>(
        xc, 512, 0, dinv, b1, N, 6);

    // ---- conv2: [N,256]x[256,128], input = xc[:,0:256) -> xc cols [256,384) ----
    gemm_kernel<<<dim3(gx, 2), blk, 0, stream>>>(
        xc, 512, W2, 128, g, 128, xc + 256, 512, dinv, (const float*)nullptr, N, 256);
    scatter_kernel<<<dim3((E * 32 + 255) / 256), blk, 0, stream>>>(
        g, xc + 256, 512, src, dst, E, 128, 5);
    finalize_kernel<<<dim3((N * 32 + 255) / 256), blk, 0, stream>>>(
        xc, 512, 256, dinv, b2, N, 5);

    // ---- conv3: [N,128]x[128,128], input = xc[:,256:384) -> xc cols [384,512) ----
    gemm_kernel<<<dim3(gx, 2), blk, 0, stream>>>(
        xc + 256, 512, W3, 128, g, 128, xc + 384, 512, dinv, (const float*)nullptr, N, 128);
    scatter_kernel<<<dim3((E * 32 + 255) / 256), blk, 0, stream>>>(
        g, xc + 384, 512, src, dst, E, 128, 5);
    finalize_kernel<<<dim3((N * 32 + 255) / 256), blk, 0, stream>>>(
        xc, 512, 384, dinv, b3, N, 5);

    // ---- final: out = xc @ W4T + b4, in place in d_out ----
    final_gemm<<<dim3(N / FBM), blk, 0, stream>>>(xc, W4T, b4);
}

// Round 3
// 1615.392 us; speedup vs baseline: 2.1646x; 2.1646x over previous
//
#include <hip/hip_runtime.h>
#include <cstdint>

#define N_NODES 100000
#define N_EDGES 300000

constexpr int BM = 64, BN = 64, BK = 32;

// C = (A @ B) * dinv[row] (+bias) ; optional second write C2 (strided concat buf)
__global__ __launch_bounds__(256)
void gemm_kernel(const float* __restrict__ A, int lda,
                 const float* __restrict__ B, int ldb,
                 float* __restrict__ C, int ldc,
                 float* __restrict__ C2, int ldc2,
                 const float* __restrict__ dinv,
                 const float* __restrict__ bias,
                 int M, int K)
{
    __shared__ float As[BK][BM + 4];   // A stored transposed: As[k][r]
    __shared__ float Bs[BK][BN + 4];

    const int tid = threadIdx.x;
    const int tx = tid & 15, ty = tid >> 4;
    const int row0 = blockIdx.x * BM, col0 = blockIdx.y * BN;

    float acc[4][4] = {};

    for (int k0 = 0; k0 < K; k0 += BK) {
#pragma unroll
        for (int it = 0; it < 2; ++it) {
            int r = (tid >> 3) + it * 32;
            int c = (tid & 7) << 2;
            float4 v = make_float4(0.f, 0.f, 0.f, 0.f);
            int gr = row0 + r;
            if (gr < M) v = *(const float4*)(A + (size_t)gr * lda + k0 + c);
            As[c + 0][r] = v.x; As[c + 1][r] = v.y;
            As[c + 2][r] = v.z; As[c + 3][r] = v.w;
        }
#pragma unroll
        for (int it = 0; it < 2; ++it) {
            int r = (tid >> 4) + it * 16;
            int c = (tid & 15) << 2;
            *(float4*)(&Bs[r][c]) = *(const float4*)(B + (size_t)(k0 + r) * ldb + col0 + c);
        }
        __syncthreads();
#pragma unroll
        for (int k = 0; k < BK; ++k) {
            float4 a4 = *(const float4*)(&As[k][ty << 2]);
            float4 b4 = *(const float4*)(&Bs[k][tx << 2]);
            float av[4] = {a4.x, a4.y, a4.z, a4.w};
            float bv[4] = {b4.x, b4.y, b4.z, b4.w};
#pragma unroll
            for (int i = 0; i < 4; ++i)
#pragma unroll
                for (int j = 0; j < 4; ++j)
                    acc[i][j] = fmaf(av[i], bv[j], acc[i][j]);
        }
        __syncthreads();
    }

#pragma unroll
    for (int i = 0; i < 4; ++i) {
        int gr = row0 + (ty << 2) + i;
        if (gr >= M) continue;
        float s = dinv ? dinv[gr] : 1.f;
        float out[4];
#pragma unroll
        for (int j = 0; j < 4; ++j) {
            int gc = col0 + (tx << 2) + j;
            float v = acc[i][j] * s;
            if (bias) v += bias[gc];
            out[j] = v;
        }
        float4 w = make_float4(out[0], out[1], out[2], out[3]);
        *(float4*)(C + (size_t)gr * ldc + col0 + (tx << 2)) = w;
        if (C2) *(float4*)(C2 + (size_t)gr * ldc2 + col0 + (tx << 2)) = w;
    }
}

// In-place final GEMM: out[N,512] = out @ B[512,512] + bias.
constexpr int FBM = 32, FBK = 16;
__global__ __launch_bounds__(256)
void final_gemm(float* __restrict__ out, const float* __restrict__ B,
                const float* __restrict__ bias)
{
    __shared__ float As[FBK][FBM + 4];
    __shared__ float Bs[FBK][512];

    const int tid = threadIdx.x;
    const int tc = tid & 31, tr = tid >> 5;     // 8 x 32 thread grid
    const size_t row0 = (size_t)blockIdx.x * FBM;

    float acc[4][16] = {};

    for (int k0 = 0; k0 < 512; k0 += FBK) {
        if (tid < 128) {
            int r = tid >> 2;           // 0..31
            int c = (tid & 3) << 2;     // 0,4,8,12
            float4 v = *(const float4*)(out + (row0 + r) * 512 + k0 + c);
            As[c + 0][r] = v.x; As[c + 1][r] = v.y;
            As[c + 2][r] = v.z; As[c + 3][r] = v.w;
        }
#pragma unroll
        for (int it = 0; it < 8; ++it) {
            int li = tid + (it << 8);        // 0..2047 float4 index
            int r = li >> 7;                 // 128 float4 per row
            int c = (li & 127) << 2;
            *(float4*)(&Bs[r][c]) = *(const float4*)(B + (size_t)(k0 + r) * 512 + c);
        }
        __syncthreads();
#pragma unroll
        for (int k = 0; k < FBK; ++k) {
            float a[4];
            *(float4*)a = *(const float4*)(&As[k][tr << 2]);
            float b[16];
#pragma unroll
            for (int jb = 0; jb < 4; ++jb)
                *(float4*)(b + (jb << 2)) = *(const float4*)(&Bs[k][(tc << 2) + (jb << 7)]);
#pragma unroll
            for (int i = 0; i < 4; ++i)
#pragma unroll
                for (int j = 0; j < 16; ++j)
                    acc[i][j] = fmaf(a[i], b[j], acc[i][j]);
        }
        __syncthreads();
    }

#pragma unroll
    for (int i = 0; i < 4; ++i) {
        size_t row = row0 + (tr << 2) + i;
#pragma unroll
        for (int jb = 0; jb < 4; ++jb) {
            int col = (tc << 2) + (jb << 7);
            float4 v;
            v.x = acc[i][(jb << 2) + 0] + bias[col + 0];
            v.y = acc[i][(jb << 2) + 1] + bias[col + 1];
            v.z = acc[i][(jb << 2) + 2] + bias[col + 2];
            v.w = acc[i][(jb << 2) + 3] + bias[col + 3];
            *(float4*)(out + row * 512 + col) = v;
        }
    }
}

// ---------- degree / CSR build ----------
__global__ __launch_bounds__(256)
void count_kernel(const int* __restrict__ dst, int* __restrict__ counts, int e)
{
    int i = blockIdx.x * 256 + threadIdx.x;
    if (i < e) atomicAdd(&counts[dst[i]], 1);
}

__global__ __launch_bounds__(256)
void dinv_kernel(const int* __restrict__ counts, float* __restrict__ dinv, int n)
{
    int i = blockIdx.x * 256 + threadIdx.x;
    if (i < n) dinv[i] = rsqrtf((float)(counts[i] + 1));   // +1 self loop
}

// exclusive scan, 3 kernels (n <= 256*512)
__global__ __launch_bounds__(256)
void scan_a(const int* __restrict__ in, int* __restrict__ partial,
            int* __restrict__ blockSums, int n)
{
    __shared__ int sh[256];
    int tid = threadIdx.x;
    int i = blockIdx.x * 256 + tid;
    int v = (i < n) ? in[i] : 0;
    sh[tid] = v;
    __syncthreads();
    for (int off = 1; off < 256; off <<= 1) {
        int t = (tid >= off) ? sh[tid - off] : 0;
        __syncthreads();
        sh[tid] += t;
        __syncthreads();
    }
    if (i < n) partial[i] = sh[tid] - v;          // exclusive
    if (tid == 255) blockSums[blockIdx.x] = sh[255];
}

__global__ __launch_bounds__(512)
void scan_b(int* __restrict__ blockSums, int nb)
{
    __shared__ int sh[512];
    int tid = threadIdx.x;
    int v = (tid < nb) ? blockSums[tid] : 0;
    sh[tid] = v;
    __syncthreads();
    for (int off = 1; off < 512; off <<= 1) {
        int t = (tid >= off) ? sh[tid - off] : 0;
        __syncthreads();
        sh[tid] += t;
        __syncthreads();
    }
    if (tid < nb) blockSums[tid] = sh[tid] - v;   // exclusive
}

__global__ __launch_bounds__(256)
void scan_c(int* __restrict__ rowptr, int* __restrict__ cursor,
            const int* __restrict__ blockSums, int n, int total)
{
    int i = blockIdx.x * 256 + threadIdx.x;
    if (i < n) {
        int v = rowptr[i] + blockSums[i >> 8];
        rowptr[i] = v;
        cursor[i] = v;
    }
    if (i == 0) rowptr[n] = total;
}

__global__ __launch_bounds__(256)
void fill_kernel(const int* __restrict__ src, const int* __restrict__ dst,
                 int* __restrict__ cursor, int* __restrict__ csr_src, int e)
{
    int i = blockIdx.x * 256 + threadIdx.x;
    if (i < e) {
        int pos = atomicAdd(&cursor[dst[i]], 1);
        csr_src[pos] = src[i];
    }
}

// xc[row, colOff+c..] = relu(dinv[row]*(g[row] + sum_{e in row} g[csr[e]]) + bias)
__global__ __launch_bounds__(256)
void gather_kernel(const float* __restrict__ g, int F, int lg2c4,
                   const int* __restrict__ rowptr, const int* __restrict__ csr,
                   const float* __restrict__ dinv, const float* __restrict__ bias,
                   float* __restrict__ xc, int colOff, int N)
{
    int idx = blockIdx.x * 256 + threadIdx.x;
    int row = idx >> lg2c4;
    if (row >= N) return;
    int c = (idx & ((1 << lg2c4) - 1)) << 2;

    float4 acc = *(const float4*)(g + (size_t)row * F + c);   // self-loop term
    int e0 = rowptr[row], e1 = rowptr[row + 1];
    for (int e = e0; e < e1; ++e) {
        int s = csr[e];
        const float4 v = *(const float4*)(g + (size_t)s * F + c);
        acc.x += v.x; acc.y += v.y; acc.z += v.z; acc.w += v.w;
    }
    float sD = dinv[row];
    float4 o;
    o.x = fmaxf(fmaf(acc.x, sD, bias[c + 0]), 0.f);
    o.y = fmaxf(fmaf(acc.y, sD, bias[c + 1]), 0.f);
    o.z = fmaxf(fmaf(acc.z, sD, bias[c + 2]), 0.f);
    o.w = fmaxf(fmaf(acc.w, sD, bias[c + 3]), 0.f);
    *(float4*)(xc + (size_t)row * 512 + colOff + c) = o;
}

__global__ __launch_bounds__(256)
void transpose_kernel(const float* __restrict__ W, float* __restrict__ WT)
{
    int idx = blockIdx.x * 256 + threadIdx.x;   // 512*512
    int i = idx >> 9, j = idx & 511;
    WT[idx] = W[(j << 9) | i];
}

// ---------- fallback (scatter) path kernels ----------
__global__ __launch_bounds__(256)
void deg_init(float* deg, int n)
{
    int i = blockIdx.x * 256 + threadIdx.x;
    if (i < n) deg[i] = 1.f;
}

__global__ __launch_bounds__(256)
void deg_count(const int* __restrict__ dst, float* __restrict__ deg, int e)
{
    int i = blockIdx.x * 256 + threadIdx.x;
    if (i < e) atomicAdd(&deg[dst[i]], 1.f);
}

__global__ __launch_bounds__(256)
void deg_rsqrt(float* deg, int n)
{
    int i = blockIdx.x * 256 + threadIdx.x;
    if (i < n) deg[i] = rsqrtf(deg[i]);
}

__global__ __launch_bounds__(256)
void scatter_kernel(const float* __restrict__ g,
                    float* __restrict__ agg, int ldagg,
                    const int* __restrict__ src, const int* __restrict__ dst,
                    int E, int F, int lg2c)
{
    int idx = blockIdx.x * 256 + threadIdx.x;
    int e = idx >> lg2c;
    if (e >= E) return;
    int c = (idx & ((1 << lg2c) - 1)) << 2;
    int s = src[e], d = dst[e];
    const float4 v = *(const float4*)(g + (size_t)s * F + c);
    float* p = agg + (size_t)d * ldagg + c;
    atomicAdd(p + 0, v.x);
    atomicAdd(p + 1, v.y);
    atomicAdd(p + 2, v.z);
    atomicAdd(p + 3, v.w);
}

__global__ __launch_bounds__(256)
void finalize_kernel(float* __restrict__ xc, int ldc, int colOff,
                     const float* __restrict__ dinv, const float* __restrict__ bias,
                     int N, int lg2c)
{
    int idx = blockIdx.x * 256 + threadIdx.x;
    int row = idx >> lg2c;
    if (row >= N) return;
    int c = (idx & ((1 << lg2c) - 1)) << 2;
    float s = dinv[row];
    float* p = xc + (size_t)row * ldc + colOff + c;
    float4 v = *(float4*)p;
    v.x = fmaxf(fmaf(v.x, s, bias[c + 0]), 0.f);
    v.y = fmaxf(fmaf(v.y, s, bias[c + 1]), 0.f);
    v.z = fmaxf(fmaf(v.z, s, bias[c + 2]), 0.f);
    v.w = fmaxf(fmaf(v.w, s, bias[c + 3]), 0.f);
    *p = v.x; *(p + 1) = v.y; *(p + 2) = v.z; *(p + 3) = v.w;
}

extern "C" void kernel_launch(void* const* d_in, const int* in_sizes, int n_in,
                              void* d_out, int out_size, void* d_ws, size_t ws_size,
                              hipStream_t stream)
{
    const float* x  = (const float*)d_in[0];
    const float* W1 = (const float*)d_in[1];
    const float* b1 = (const float*)d_in[2];
    const float* W2 = (const float*)d_in[3];
    const float* b2 = (const float*)d_in[4];
    const float* W3 = (const float*)d_in[5];
    const float* b3 = (const float*)d_in[6];
    const float* W4 = (const float*)d_in[7];
    const float* b4 = (const float*)d_in[8];
    const int*   ei = (const int*)d_in[9];
    const int* src = ei;
    const int* dst = ei + N_EDGES;

    const int N = N_NODES, E = N_EDGES;

    // CSR-path workspace layout
    const size_t O_DINV = 0;
    const size_t O_CNT  = 401408;                 // counts / cursor (reused)
    const size_t O_ROW  = 802816;                 // rowptr [N+1]
    const size_t O_BS   = 1204224;                // block sums (512 ints)
    const size_t O_CSR  = 1208320;                // csr_src [E]
    const size_t O_W4T  = 2412544;
    const size_t O_G    = 3461120;
    const size_t WS_CSR = O_G + (size_t)N * 256 * 4;   // ~105.9 MB
    // fallback layout (round-2 proven): dinv | W4T | g
    const size_t F_W4T  = 401408;
    const size_t F_G    = F_W4T + 512 * 512 * 4;
    const size_t WS_FB  = F_G + (size_t)N * 256 * 4;   // ~103.85 MB

    char* ws = (char*)d_ws;
    float* xc = (float*)d_out;
    dim3 blk(256);
    int gx = (N + BM - 1) / BM;

    if (ws_size >= WS_CSR) {
        float* dinv  = (float*)(ws + O_DINV);
        int* counts  = (int*)(ws + O_CNT);
        int* rowptr  = (int*)(ws + O_ROW);
        int* bsums   = (int*)(ws + O_BS);
        int* csr     = (int*)(ws + O_CSR);
        float* W4T   = (float*)(ws + O_W4T);
        float* g     = (float*)(ws + O_G);

        const int nb = (N + 255) / 256;   // 391

        hipMemsetAsync(counts, 0, (size_t)N * 4, stream);
        count_kernel<<<dim3((E + 255) / 256), blk, 0, stream>>>(dst, counts, E);
        dinv_kernel<<<dim3(nb), blk, 0, stream>>>(counts, dinv, N);
        scan_a<<<dim3(nb), blk, 0, stream>>>(counts, rowptr, bsums, N);
        scan_b<<<dim3(1), dim3(512), 0, stream>>>(bsums, nb);
        scan_c<<<dim3(nb), blk, 0, stream>>>(rowptr, counts /*cursor*/, bsums, N, E);
        fill_kernel<<<dim3((E + 255) / 256), blk, 0, stream>>>(src, dst, counts, csr, E);
        transpose_kernel<<<dim3(1024), blk, 0, stream>>>(W4, W4T);

        // conv1
        gemm_kernel<<<dim3(gx, 4), blk, 0, stream>>>(
            x, 512, W1, 256, g, 256, (float*)nullptr, 0, dinv, (const float*)nullptr, N, 512);
        gather_kernel<<<dim3((N * 64 + 255) / 256), blk, 0, stream>>>(
            g, 256, 6, rowptr, csr, dinv, b1, xc, 0, N);
        // conv2
        gemm_kernel<<<dim3(gx, 2), blk, 0, stream>>>(
            xc, 512, W2, 128, g, 128, (float*)nullptr, 0, dinv, (const float*)nullptr, N, 256);
        gather_kernel<<<dim3((N * 32 + 255) / 256), blk, 0, stream>>>(
            g, 128, 5, rowptr, csr, dinv, b2, xc, 256, N);
        // conv3
        gemm_kernel<<<dim3(gx, 2), blk, 0, stream>>>(
            xc + 256, 512, W3, 128, g, 128, (float*)nullptr, 0, dinv, (const float*)nullptr, N, 128);
        gather_kernel<<<dim3((N * 32 + 255) / 256), blk, 0, stream>>>(
            g, 128, 5, rowptr, csr, dinv, b3, xc, 384, N);

        final_gemm<<<dim3(N / FBM), blk, 0, stream>>>(xc, W4T, b4);
    } else if (ws_size >= WS_FB) {
        // fallback: round-2 scatter path
        float* dinv = (float*)ws;
        float* W4T  = (float*)(ws + F_W4T);
        float* g    = (float*)(ws + F_G);

        deg_init<<<dim3((N + 255) / 256), blk, 0, stream>>>(dinv, N);
        deg_count<<<dim3((E + 255) / 256), blk, 0, stream>>>(dst, dinv, E);
        deg_rsqrt<<<dim3((N + 255) / 256), blk, 0, stream>>>(dinv, N);
        transpose_kernel<<<dim3(1024), blk, 0, stream>>>(W4, W4T);

        gemm_kernel<<<dim3(gx, 4), blk, 0, stream>>>(
            x, 512, W1, 256, g, 256, xc + 0, 512, dinv, (const float*)nullptr, N, 512);
        scatter_kernel<<<dim3((E * 64 + 255) / 256), blk, 0, stream>>>(
            g, xc + 0, 512, src, dst, E, 256, 6);
        finalize_kernel<<<dim3((N * 64 + 255) / 256), blk, 0, stream>>>(
            xc, 512, 0, dinv, b1, N, 6);

        gemm_kernel<<<dim3(gx, 2), blk, 0, stream>>>(
            xc, 512, W2, 128, g, 128, xc + 256, 512, dinv, (const float*)nullptr, N, 256);
        scatter_kernel<<<dim3((E * 32 + 255) / 256), blk, 0, stream>>>(
            g, xc + 256, 512, src, dst, E, 128, 5);
        finalize_kernel<<<dim3((N * 32 + 255) / 256), blk, 0, stream>>>(
            xc, 512, 256, dinv, b2, N, 5);

        gemm_kernel<<<dim3(gx, 2), blk, 0, stream>>>(
            xc + 256, 512, W3, 128, g, 128, xc + 384, 512, dinv, (const float*)nullptr, N, 128);
        scatter_kernel<<<dim3((E * 32 + 255) / 256), blk, 0, stream>>>(
            g, xc + 384, 512, src, dst, E, 128, 5);
        finalize_kernel<<<dim3((N * 32 + 255) / 256), blk, 0, stream>>>(
            xc, 512, 384, dinv, b3, N, 5);

        final_gemm<<<dim3(N / FBM), blk, 0, stream>>>(xc, W4T, b4);
    }
}